// Round 1
// baseline (383.501 us; speedup 1.0000x reference)
//
#include <hip/hip_runtime.h>

#define BN_EPS 1e-5f

typedef __attribute__((ext_vector_type(8))) short bf16x8;
typedef __attribute__((ext_vector_type(4))) float f32x4;

// ---------------------------------------------------------------------------
// Weight prep: per output channel o, alpha[o] = mean|w[o,:,:,:]| (2304 elems),
// S[t][o][c] = sign(w[o][c][kh][kw]) as bf16 bit pattern (t = kh*3+kw).
// Layout [9][256][256] so MFMA A-fragments load 8 contiguous c per lane.
// ---------------------------------------------------------------------------
__global__ void prep_w_kernel(const float* __restrict__ w,
                              unsigned short* __restrict__ S,
                              float* __restrict__ alpha) {
    int o = blockIdx.x;   // 256
    int c = threadIdx.x;  // 256
    const float* wp = w + (o * 256 + c) * 9;
    float s = 0.f;
    unsigned short sg[9];
#pragma unroll
    for (int j = 0; j < 9; ++j) {
        float v = wp[j];
        s += fabsf(v);
        sg[j] = v > 0.f ? (unsigned short)0x3F80u
                        : (v < 0.f ? (unsigned short)0xBF80u : (unsigned short)0u);
    }
    __shared__ float red[256];
    red[c] = s;
    __syncthreads();
    for (int off = 128; off > 0; off >>= 1) {
        if (c < off) red[c] += red[c + off];
        __syncthreads();
    }
    if (c == 0) alpha[o] = red[0] / 2304.0f;
#pragma unroll
    for (int j = 0; j < 9; ++j)
        S[(j * 256 + o) * 256 + c] = sg[j];
}

// ---------------------------------------------------------------------------
// Pass 1 reduction: partials[bid] = block-sum of |bn1(x)| (deterministic).
// x is NCHW [32][256][1024] f32, read as float4 (all 4 elems share channel).
// ---------------------------------------------------------------------------
__global__ void bnabs_reduce_kernel(const float* __restrict__ x,
                                    const float* __restrict__ gamma,
                                    const float* __restrict__ beta,
                                    const float* __restrict__ mean,
                                    const float* __restrict__ var,
                                    float* __restrict__ partials) {
    int tid = blockIdx.x * blockDim.x + threadIdx.x;
    int nthreads = gridDim.x * blockDim.x;
    const float4* x4 = (const float4*)x;
    float s = 0.f;
    for (int i = tid; i < 2097152; i += nthreads) {
        int c = (i >> 8) & 255;
        float inv = gamma[c] * rsqrtf(var[c] + BN_EPS);
        float b = beta[c] - mean[c] * inv;
        float4 v = x4[i];
        s += fabsf(v.x * inv + b) + fabsf(v.y * inv + b) +
             fabsf(v.z * inv + b) + fabsf(v.w * inv + b);
    }
    __shared__ float red[256];
    red[threadIdx.x] = s;
    __syncthreads();
    for (int off = 128; off > 0; off >>= 1) {
        if (threadIdx.x < off) red[threadIdx.x] += red[threadIdx.x + off];
        __syncthreads();
    }
    if (threadIdx.x == 0) partials[blockIdx.x] = red[0];
}

// deterministic single-block sum of n partials; *out = sum * scale
__global__ void finalize_delta_kernel(const float* __restrict__ partials, int n,
                                      float scale, float* __restrict__ out) {
    __shared__ float red[256];
    float s = 0.f;
    for (int i = threadIdx.x; i < n; i += 256) s += partials[i];
    red[threadIdx.x] = s;
    __syncthreads();
    for (int off = 128; off > 0; off >>= 1) {
        if (threadIdx.x < off) red[threadIdx.x] += red[threadIdx.x + off];
        __syncthreads();
    }
    if (threadIdx.x == 0) *out = red[0] * scale;
}

// ---------------------------------------------------------------------------
// Quantize: q (NHWC, bf16 bit patterns of {-1,0,+1}) from bn(src) vs *delta.
// idx is NHWC flat: c = idx&255, pix = idx>>8 (n*1024+p). Coalesced writes.
// ---------------------------------------------------------------------------
__global__ void quant_kernel(const float* __restrict__ src,
                             const float* __restrict__ gamma,
                             const float* __restrict__ beta,
                             const float* __restrict__ mean,
                             const float* __restrict__ var,
                             const float* __restrict__ deltaPtr,
                             unsigned short* __restrict__ q) {
    int idx = blockIdx.x * 256 + threadIdx.x;  // 0 .. 8388607
    float delta = *deltaPtr;
    int c = idx & 255;
    int pix = idx >> 8;        // n*1024 + p
    int n = pix >> 10;
    int p = pix & 1023;
    float inv = gamma[c] * rsqrtf(var[c] + BN_EPS);
    float b = beta[c] - mean[c] * inv;
    float v = src[n * 262144 + c * 1024 + p] * inv + b;
    q[idx] = v > delta ? (unsigned short)0x3F80u
                       : (v < -delta ? (unsigned short)0xBF80u : (unsigned short)0u);
}

// ---------------------------------------------------------------------------
// TBN conv as 9 shifted GEMMs with bf16 MFMA 16x16x32.
// Block: 256 thr = 4 waves; block tile 128(o) x 128(pix); wave tile 64x64.
// A[m=o][k=c] = S[t], B[k=c][n=pix] = q (NHWC). D: row=(l>>4)*4+r, col=l&15.
// Epilogue: out = resid + alpha[o]*acc; optional fused sum|bn2(out)| partial.
// ---------------------------------------------------------------------------
template <bool FUSE>
__global__ __launch_bounds__(256) void tbn_conv_kernel(
    const unsigned short* __restrict__ q,   // [32][32][32][256] bf16 bits
    const unsigned short* __restrict__ S,   // [9][256][256] bf16 bits
    const float* __restrict__ alpha,        // [256]
    const float* __restrict__ resid,        // [32][256][1024] f32 NCHW
    float* __restrict__ out,                // [32][256][1024] f32 NCHW
    const float* __restrict__ gamma, const float* __restrict__ beta,
    const float* __restrict__ mean, const float* __restrict__ var,
    float* __restrict__ partials) {
    int bid = blockIdx.x;          // 512 = 32 n * 2 ob * 8 pb
    int n = bid >> 4;
    int ob = (bid >> 3) & 1;
    int pb = bid & 7;
    int tid = threadIdx.x;
    int lane = tid & 63;
    int wid = tid >> 6;
    int o0 = ob * 128 + (wid >> 1) * 64;
    int p0 = pb * 128 + (wid & 1) * 64;
    int l15 = lane & 15;
    int kg = lane >> 4;  // k-group 0..3

    f32x4 acc[4][4];
#pragma unroll
    for (int m = 0; m < 4; ++m)
#pragma unroll
        for (int nn = 0; nn < 4; ++nn) {
            acc[m][nn][0] = 0.f; acc[m][nn][1] = 0.f;
            acc[m][nn][2] = 0.f; acc[m][nn][3] = 0.f;
        }

    bf16x8 bzero;
#pragma unroll
    for (int i = 0; i < 8; ++i) bzero[i] = 0;

    const unsigned short* qn = q + n * (32 * 32 * 256);

    for (int t = 0; t < 9; ++t) {
        int kh = t / 3 - 1;
        int kw = t % 3 - 1;
#pragma unroll 1
        for (int kc = 0; kc < 8; ++kc) {
            int c0 = kc * 32 + kg * 8;
            bf16x8 a[4], b[4];
#pragma unroll
            for (int m = 0; m < 4; ++m) {
                int o = o0 + m * 16 + l15;
                a[m] = *(const bf16x8*)(S + (t * 256 + o) * 256 + c0);
            }
#pragma unroll
            for (int nn = 0; nn < 4; ++nn) {
                int p = p0 + nn * 16 + l15;
                int y = (p >> 5) + kh;
                int x = (p & 31) + kw;
                bool valid = (y >= 0) && (y < 32) && (x >= 0) && (x < 32);
                int cy = y < 0 ? 0 : (y > 31 ? 31 : y);
                int cx = x < 0 ? 0 : (x > 31 ? 31 : x);
                bf16x8 v = *(const bf16x8*)(qn + (cy * 32 + cx) * 256 + c0);
                b[nn] = valid ? v : bzero;
            }
#pragma unroll
            for (int m = 0; m < 4; ++m)
#pragma unroll
                for (int nn = 0; nn < 4; ++nn)
                    acc[m][nn] = __builtin_amdgcn_mfma_f32_16x16x32_bf16(
                        a[m], b[nn], acc[m][nn], 0, 0, 0);
        }
    }

    float psum = 0.f;
#pragma unroll
    for (int m = 0; m < 4; ++m) {
#pragma unroll
        for (int r = 0; r < 4; ++r) {
            int o = o0 + m * 16 + kg * 4 + r;
            float al = alpha[o];
            float inv = 0.f, bb = 0.f;
            if (FUSE) {
                inv = gamma[o] * rsqrtf(var[o] + BN_EPS);
                bb = beta[o] - mean[o] * inv;
            }
#pragma unroll
            for (int nn = 0; nn < 4; ++nn) {
                int p = p0 + nn * 16 + l15;
                int off = n * 262144 + o * 1024 + p;
                float h = resid[off] + al * acc[m][nn][r];
                out[off] = h;
                if (FUSE) psum += fabsf(h * inv + bb);
            }
        }
    }
    if (FUSE) {
        __shared__ float red[256];
        red[tid] = psum;
        __syncthreads();
        for (int off = 128; off > 0; off >>= 1) {
            if (tid < off) red[tid] += red[tid + off];
            __syncthreads();
        }
        if (tid == 0) partials[bid] = red[0];
    }
}

// ---------------------------------------------------------------------------
extern "C" void kernel_launch(void* const* d_in, const int* in_sizes, int n_in,
                              void* d_out, int out_size, void* d_ws, size_t ws_size,
                              hipStream_t stream) {
    (void)in_sizes; (void)n_in; (void)out_size; (void)ws_size;
    const float* x  = (const float*)d_in[0];
    const float* w1 = (const float*)d_in[1];
    const float* w2 = (const float*)d_in[2];
    const float* g1 = (const float*)d_in[3];
    const float* b1 = (const float*)d_in[4];
    const float* m1 = (const float*)d_in[5];
    const float* v1 = (const float*)d_in[6];
    const float* g2 = (const float*)d_in[7];
    const float* b2 = (const float*)d_in[8];
    const float* m2 = (const float*)d_in[9];
    const float* v2 = (const float*)d_in[10];
    float* out = (float*)d_out;
    char* ws = (char*)d_ws;

    float* delta1 = (float*)(ws + 0);
    float* delta2 = (float*)(ws + 4);
    float* red1   = (float*)(ws + 1024);              // 4096 floats
    float* redc   = (float*)(ws + 1024 + 16384);      // 512 floats
    float* alpha1 = (float*)(ws + 32768);
    float* alpha2 = (float*)(ws + 36864);
    unsigned short* S1 = (unsigned short*)(ws + (size_t)(1 << 20));
    unsigned short* S2 = (unsigned short*)(ws + (size_t)(3 << 20));
    unsigned short* q1 = (unsigned short*)(ws + (size_t)8 * 1024 * 1024);
    unsigned short* q2 = (unsigned short*)(ws + (size_t)32 * 1024 * 1024);
    float* h           = (float*)(ws + (size_t)56 * 1024 * 1024);

    const float kScale = 0.7f / 8388608.0f;

    prep_w_kernel<<<256, 256, 0, stream>>>(w1, S1, alpha1);
    prep_w_kernel<<<256, 256, 0, stream>>>(w2, S2, alpha2);
    bnabs_reduce_kernel<<<4096, 256, 0, stream>>>(x, g1, b1, m1, v1, red1);
    finalize_delta_kernel<<<1, 256, 0, stream>>>(red1, 4096, kScale, delta1);
    quant_kernel<<<32768, 256, 0, stream>>>(x, g1, b1, m1, v1, delta1, q1);
    tbn_conv_kernel<true><<<512, 256, 0, stream>>>(q1, S1, alpha1, x, h,
                                                   g2, b2, m2, v2, redc);
    finalize_delta_kernel<<<1, 256, 0, stream>>>(redc, 512, kScale, delta2);
    quant_kernel<<<32768, 256, 0, stream>>>(h, g2, b2, m2, v2, delta2, q2);
    tbn_conv_kernel<false><<<512, 256, 0, stream>>>(q2, S2, alpha2, h, out,
                                                    nullptr, nullptr, nullptr,
                                                    nullptr, nullptr);
}

// Round 2
// 257.595 us; speedup vs baseline: 1.4888x; 1.4888x over previous
//
#include <hip/hip_runtime.h>

#define BN_EPS 1e-5f
#define QN_STRIDE 295936   // 34*34*256 i8 per image (1-pixel zero halo)

typedef __attribute__((ext_vector_type(4))) int int32x4;

// ---------------------------------------------------------------------------
// Weight prep: alpha[o] = mean|w[o]|, S[t][o][c] = sign as i8 {-1,0,+1}.
// ---------------------------------------------------------------------------
__global__ void prep_w_kernel(const float* __restrict__ w,
                              signed char* __restrict__ S,
                              float* __restrict__ alpha) {
    int o = blockIdx.x;   // 256
    int c = threadIdx.x;  // 256
    const float* wp = w + (o * 256 + c) * 9;
    float s = 0.f;
    signed char sg[9];
#pragma unroll
    for (int j = 0; j < 9; ++j) {
        float v = wp[j];
        s += fabsf(v);
        sg[j] = v > 0.f ? 1 : (v < 0.f ? -1 : 0);
    }
    __shared__ float red[256];
    red[c] = s;
    __syncthreads();
    for (int off = 128; off > 0; off >>= 1) {
        if (c < off) red[c] += red[c + off];
        __syncthreads();
    }
    if (c == 0) alpha[o] = red[0] / 2304.0f;
#pragma unroll
    for (int j = 0; j < 9; ++j)
        S[(j * 256 + o) * 256 + c] = sg[j];
}

// ---------------------------------------------------------------------------
// partials[bid] = block-sum of |bn1(x)| (deterministic tree).
// ---------------------------------------------------------------------------
__global__ void bnabs_reduce_kernel(const float* __restrict__ x,
                                    const float* __restrict__ gamma,
                                    const float* __restrict__ beta,
                                    const float* __restrict__ mean,
                                    const float* __restrict__ var,
                                    float* __restrict__ partials) {
    int tid = blockIdx.x * blockDim.x + threadIdx.x;
    int nthreads = gridDim.x * blockDim.x;
    const float4* x4 = (const float4*)x;
    float s = 0.f;
    for (int i = tid; i < 2097152; i += nthreads) {
        int c = (i >> 8) & 255;
        float inv = gamma[c] * rsqrtf(var[c] + BN_EPS);
        float b = beta[c] - mean[c] * inv;
        float4 v = x4[i];
        s += fabsf(v.x * inv + b) + fabsf(v.y * inv + b) +
             fabsf(v.z * inv + b) + fabsf(v.w * inv + b);
    }
    __shared__ float red[256];
    red[threadIdx.x] = s;
    __syncthreads();
    for (int off = 128; off > 0; off >>= 1) {
        if (threadIdx.x < off) red[threadIdx.x] += red[threadIdx.x + off];
        __syncthreads();
    }
    if (threadIdx.x == 0) partials[blockIdx.x] = red[0];
}

__global__ void finalize_delta_kernel(const float* __restrict__ partials, int n,
                                      float scale, float* __restrict__ out) {
    __shared__ float red[256];
    float s = 0.f;
    for (int i = threadIdx.x; i < n; i += 256) s += partials[i];
    red[threadIdx.x] = s;
    __syncthreads();
    for (int off = 128; off > 0; off >>= 1) {
        if (threadIdx.x < off) red[threadIdx.x] += red[threadIdx.x + off];
        __syncthreads();
    }
    if (threadIdx.x == 0) *out = red[0] * scale;
}

// ---------------------------------------------------------------------------
// Quantize into padded NHWC i8: q[n][y+1][x+1][c] in {-1,0,+1}; halo stays 0.
// Coalesced f32 reads (lanes along p), BN params via LDS, 16B packed writes.
// Block = 256 thr: 64 pixels x 256 c; thread = (pixel, 64-channel slab).
// ---------------------------------------------------------------------------
__global__ __launch_bounds__(256) void quant_kernel(
    const float* __restrict__ src,
    const float* __restrict__ gamma, const float* __restrict__ beta,
    const float* __restrict__ mean, const float* __restrict__ var,
    const float* __restrict__ deltaPtr, signed char* __restrict__ q) {
    __shared__ float sInv[256], sB[256];
    int tid = threadIdx.x;
    {
        float inv = gamma[tid] * rsqrtf(var[tid] + BN_EPS);
        sInv[tid] = inv;
        sB[tid] = beta[tid] - mean[tid] * inv;
    }
    __syncthreads();
    int bid = blockIdx.x;          // 512 = 32 n * 16 pblk
    int n = bid >> 4;
    int p0 = (bid & 15) * 64;
    int l = tid & 63, wv = tid >> 6;
    int p = p0 + l;
    int y = p >> 5, x = p & 31;
    float delta = *deltaPtr;
    const float* sp = src + (size_t)n * 262144 + p;
    signed char* qp = q + (size_t)n * QN_STRIDE + ((y + 1) * 34 + (x + 1)) * 256 + wv * 64;
#pragma unroll
    for (int chunk = 0; chunk < 4; ++chunk) {
        int w4[4];
#pragma unroll
        for (int d = 0; d < 4; ++d) {
            int wrd = 0;
#pragma unroll
            for (int j = 0; j < 4; ++j) {
                int c = wv * 64 + chunk * 16 + d * 4 + j;
                float s = sp[c * 1024] * sInv[c] + sB[c];
                int qv = s > delta ? 1 : (s < -delta ? -1 : 0);
                wrd |= (qv & 255) << (8 * j);
            }
            w4[d] = wrd;
        }
        int32x4 vv;
        vv[0] = w4[0]; vv[1] = w4[1]; vv[2] = w4[2]; vv[3] = w4[3];
        *(int32x4*)(qp + chunk * 16) = vv;
    }
}

// ---------------------------------------------------------------------------
// TBN conv, i8 MFMA 16x16x64, 9 shifted GEMMs over zero-padded q.
// Block 256 thr = 4 waves; tile 64(o) x 128(p); wave tile 32 x 64.
// Register double-buffered fragments; XCD-chunked block swizzle.
// ---------------------------------------------------------------------------
template <bool FUSE>
__global__ __launch_bounds__(256, 4) void tbn_conv_kernel(
    const signed char* __restrict__ q,   // [32][34][34][256] i8
    const signed char* __restrict__ S,   // [9][256][256] i8
    const float* __restrict__ alpha,     // [256]
    const float* __restrict__ resid,     // [32][256][1024] f32
    float* __restrict__ out,             // [32][256][1024] f32
    const float* __restrict__ gamma, const float* __restrict__ beta,
    const float* __restrict__ mean, const float* __restrict__ var,
    float* __restrict__ partials) {
    int wg = (blockIdx.x & 7) * 128 + (blockIdx.x >> 3);  // bijective, 1024%8==0
    int n = wg >> 5;
    int pb = (wg >> 2) & 7;
    int ob = wg & 3;
    int tid = threadIdx.x, lane = tid & 63, wid = tid >> 6;
    int l15 = lane & 15, kg = lane >> 4;

    __shared__ float sAl[64], sInvS[64], sBS[64];
    __shared__ float red[256];
    if (tid < 64) {
        int o = ob * 64 + tid;
        sAl[tid] = alpha[o];
        if (FUSE) {
            float inv = gamma[o] * rsqrtf(var[o] + BN_EPS);
            sInvS[tid] = inv;
            sBS[tid] = beta[o] - mean[o] * inv;
        }
    }
    __syncthreads();

    int oW = (wid >> 1) * 32, pW = (wid & 1) * 64;
    int o0 = ob * 64 + oW, p0 = pb * 128 + pW;

    int aOff0 = (o0 + l15) * 256 + kg * 16;
    int aOff1 = aOff0 + 16 * 256;
    int bOff[4], pLane[4];
#pragma unroll
    for (int nn = 0; nn < 4; ++nn) {
        int p = p0 + nn * 16 + l15;
        pLane[nn] = p;
        int y = p >> 5, x = p & 31;
        bOff[nn] = ((y + 1) * 34 + (x + 1)) * 256 + kg * 16;
    }
    const signed char* qn = q + (size_t)n * QN_STRIDE;

    int32x4 acc[2][4];
#pragma unroll
    for (int m2 = 0; m2 < 2; ++m2)
#pragma unroll
        for (int nn = 0; nn < 4; ++nn) {
            acc[m2][nn][0] = 0; acc[m2][nn][1] = 0;
            acc[m2][nn][2] = 0; acc[m2][nn][3] = 0;
        }

    int32x4 fa0[2], fb0[4], fa1[2], fb1[4];

#define LOADF(FA, FB, IDX)                                                   \
    do {                                                                     \
        int idx_ = (IDX);                                                    \
        int tap_ = idx_ >> 2, kc_ = idx_ & 3;                                \
        int kh1_ = (tap_ * 11) >> 5; /* (tap/3) for 0..8 */                  \
        int kw_ = tap_ - kh1_ * 3 - 1;                                       \
        const signed char* pa_ = S + tap_ * 65536 + kc_ * 64;                \
        const signed char* pb_ = qn + ((kh1_ - 1) * 34 + kw_) * 256 + kc_ * 64; \
        FA[0] = *(const int32x4*)(pa_ + aOff0);                              \
        FA[1] = *(const int32x4*)(pa_ + aOff1);                              \
        FB[0] = *(const int32x4*)(pb_ + bOff[0]);                            \
        FB[1] = *(const int32x4*)(pb_ + bOff[1]);                            \
        FB[2] = *(const int32x4*)(pb_ + bOff[2]);                            \
        FB[3] = *(const int32x4*)(pb_ + bOff[3]);                            \
    } while (0)

#define MFMA8(FA, FB)                                                        \
    do {                                                                     \
        _Pragma("unroll")                                                    \
        for (int m2 = 0; m2 < 2; ++m2)                                       \
            _Pragma("unroll")                                                \
            for (int nn = 0; nn < 4; ++nn)                                   \
                acc[m2][nn] = __builtin_amdgcn_mfma_i32_16x16x64_i8(         \
                    FA[m2], FB[nn], acc[m2][nn], 0, 0, 0);                   \
    } while (0)

    LOADF(fa0, fb0, 0);
#pragma unroll
    for (int i = 0; i < 36; i += 2) {
        LOADF(fa1, fb1, i + 1);
        MFMA8(fa0, fb0);
        if (i + 2 < 36) LOADF(fa0, fb0, i + 2);
        MFMA8(fa1, fb1);
    }
#undef LOADF
#undef MFMA8

    // D layout (16x16): col = lane&15 (pixel), row = kg*4 + r (o within 16)
    float psum = 0.f;
#pragma unroll
    for (int m2 = 0; m2 < 2; ++m2) {
#pragma unroll
        for (int r = 0; r < 4; ++r) {
            int oLoc = oW + m2 * 16 + kg * 4 + r;  // 0..63 within block
            int o = ob * 64 + oLoc;
            float al = sAl[oLoc];
            float inv = 0.f, bb = 0.f;
            if (FUSE) { inv = sInvS[oLoc]; bb = sBS[oLoc]; }
            const float* rp = resid + (size_t)n * 262144 + o * 1024;
            float* op = out + (size_t)n * 262144 + o * 1024;
#pragma unroll
            for (int nn = 0; nn < 4; ++nn) {
                float h = rp[pLane[nn]] + al * (float)acc[m2][nn][r];
                op[pLane[nn]] = h;
                if (FUSE) psum += fabsf(h * inv + bb);
            }
        }
    }
    if (FUSE) {
        red[tid] = psum;
        __syncthreads();
        for (int off = 128; off > 0; off >>= 1) {
            if (tid < off) red[tid] += red[tid + off];
            __syncthreads();
        }
        if (tid == 0) partials[wg] = red[0];
    }
}

// ---------------------------------------------------------------------------
extern "C" void kernel_launch(void* const* d_in, const int* in_sizes, int n_in,
                              void* d_out, int out_size, void* d_ws, size_t ws_size,
                              hipStream_t stream) {
    (void)in_sizes; (void)n_in; (void)out_size; (void)ws_size;
    const float* x  = (const float*)d_in[0];
    const float* w1 = (const float*)d_in[1];
    const float* w2 = (const float*)d_in[2];
    const float* g1 = (const float*)d_in[3];
    const float* b1 = (const float*)d_in[4];
    const float* m1 = (const float*)d_in[5];
    const float* v1 = (const float*)d_in[6];
    const float* g2 = (const float*)d_in[7];
    const float* b2 = (const float*)d_in[8];
    const float* m2 = (const float*)d_in[9];
    const float* v2 = (const float*)d_in[10];
    float* out = (float*)d_out;
    char* ws = (char*)d_ws;

    float* delta1 = (float*)(ws + 0);
    float* delta2 = (float*)(ws + 4);
    float* red1   = (float*)(ws + 4096);       // 4096 floats
    float* redc   = (float*)(ws + 20480);      // 1024 floats
    float* alpha1 = (float*)(ws + 24576);
    float* alpha2 = (float*)(ws + 25600);
    signed char* S1 = (signed char*)(ws + ((size_t)1 << 20));
    signed char* S2 = (signed char*)(ws + ((size_t)2 << 20));
    signed char* q1 = (signed char*)(ws + ((size_t)4 << 20));
    signed char* q2 = (signed char*)(ws + ((size_t)16 << 20));
    float* h        = (float*)(ws + ((size_t)32 << 20));

    const float kScale = 0.7f / 8388608.0f;

    hipMemsetAsync(q1, 0, (size_t)32 * QN_STRIDE, stream);
    hipMemsetAsync(q2, 0, (size_t)32 * QN_STRIDE, stream);
    prep_w_kernel<<<256, 256, 0, stream>>>(w1, S1, alpha1);
    prep_w_kernel<<<256, 256, 0, stream>>>(w2, S2, alpha2);
    bnabs_reduce_kernel<<<4096, 256, 0, stream>>>(x, g1, b1, m1, v1, red1);
    finalize_delta_kernel<<<1, 256, 0, stream>>>(red1, 4096, kScale, delta1);
    quant_kernel<<<512, 256, 0, stream>>>(x, g1, b1, m1, v1, delta1, q1);
    tbn_conv_kernel<true><<<1024, 256, 0, stream>>>(q1, S1, alpha1, x, h,
                                                    g2, b2, m2, v2, redc);
    finalize_delta_kernel<<<1, 256, 0, stream>>>(redc, 1024, kScale, delta2);
    quant_kernel<<<512, 256, 0, stream>>>(h, g2, b2, m2, v2, delta2, q2);
    tbn_conv_kernel<false><<<1024, 256, 0, stream>>>(q2, S2, alpha2, h, out,
                                                     nullptr, nullptr, nullptr,
                                                     nullptr, nullptr);
}

// Round 3
// 143.689 us; speedup vs baseline: 2.6690x; 1.7927x over previous
//
#include <hip/hip_runtime.h>

#define BN_EPS 1e-5f
#define QR_IMG   73984      // 34*34*64 bytes per (kc, image)
#define QR_KC    2367488    // 32 * QR_IMG
#define SR_TAPKC 16384      // 256*64 bytes per (t,kc)

typedef __attribute__((ext_vector_type(4))) int int32x4;

// ---------------------------------------------------------------------------
// Weight prep: alpha[o] = mean|w[o]| ; Sr[(t*4+kc)*256 + o][64] = sign i8.
// One block per o; LDS transpose so Sr writes are 16B contiguous.
// ---------------------------------------------------------------------------
__global__ void prep_w_kernel(const float* __restrict__ w,
                              signed char* __restrict__ Sr,
                              float* __restrict__ alpha) {
    int o = blockIdx.x;   // 256
    int c = threadIdx.x;  // 256
    const float* wp = w + (o * 256 + c) * 9;
    float s = 0.f;
    __shared__ __align__(16) signed char lsg[9][256];
    __shared__ float red[256];
#pragma unroll
    for (int j = 0; j < 9; ++j) {
        float v = wp[j];
        s += fabsf(v);
        lsg[j][c] = v > 0.f ? 1 : (v < 0.f ? -1 : 0);
    }
    red[c] = s;
    __syncthreads();
    for (int off = 128; off > 0; off >>= 1) {
        if (c < off) red[c] += red[c + off];
        __syncthreads();
    }
    if (c == 0) alpha[o] = red[0] / 2304.0f;
    if (c < 144) {
        int t = c / 16, u = c % 16;
        int c0 = u * 16;
        int kc = c0 >> 6, cb = c0 & 63;
        int32x4 v = *(const int32x4*)(&lsg[t][c0]);
        *(int32x4*)(Sr + (size_t)((t * 4 + kc) * 256 + o) * 64 + cb) = v;
    }
}

// ---------------------------------------------------------------------------
// partials[bid] = block-sum of |bn1(x)| (deterministic tree).
// ---------------------------------------------------------------------------
__global__ void bnabs_reduce_kernel(const float* __restrict__ x,
                                    const float* __restrict__ gamma,
                                    const float* __restrict__ beta,
                                    const float* __restrict__ mean,
                                    const float* __restrict__ var,
                                    float* __restrict__ partials) {
    int tid = blockIdx.x * blockDim.x + threadIdx.x;
    int nthreads = gridDim.x * blockDim.x;
    const float4* x4 = (const float4*)x;
    float s = 0.f;
    for (int i = tid; i < 2097152; i += nthreads) {
        int c = (i >> 8) & 255;
        float inv = gamma[c] * rsqrtf(var[c] + BN_EPS);
        float b = beta[c] - mean[c] * inv;
        float4 v = x4[i];
        s += fabsf(v.x * inv + b) + fabsf(v.y * inv + b) +
             fabsf(v.z * inv + b) + fabsf(v.w * inv + b);
    }
    __shared__ float red[256];
    red[threadIdx.x] = s;
    __syncthreads();
    for (int off = 128; off > 0; off >>= 1) {
        if (threadIdx.x < off) red[threadIdx.x] += red[threadIdx.x + off];
        __syncthreads();
    }
    if (threadIdx.x == 0) partials[blockIdx.x] = red[0];
}

__global__ void finalize_delta_kernel(const float* __restrict__ partials, int n,
                                      float scale, float* __restrict__ out) {
    __shared__ float red[256];
    float s = 0.f;
    for (int i = threadIdx.x; i < n; i += 256) s += partials[i];
    red[threadIdx.x] = s;
    __syncthreads();
    for (int off = 128; off > 0; off >>= 1) {
        if (threadIdx.x < off) red[threadIdx.x] += red[threadIdx.x + off];
        __syncthreads();
    }
    if (threadIdx.x == 0) *out = red[0] * scale;
}

// ---------------------------------------------------------------------------
// Quantize into k-chunk-major padded layout:
// qr[kc][n][y+1][x+1][64] i8 in {-1,0,+1}; halo stays 0.
// Block 256 thr = 64 px x 4 chunk-slabs; writes 64B contiguous per thread.
// ---------------------------------------------------------------------------
__global__ __launch_bounds__(256) void quant_kernel(
    const float* __restrict__ src,
    const float* __restrict__ gamma, const float* __restrict__ beta,
    const float* __restrict__ mean, const float* __restrict__ var,
    const float* __restrict__ deltaPtr, signed char* __restrict__ qr) {
    __shared__ float sInv[256], sB[256];
    int tid = threadIdx.x;
    {
        float inv = gamma[tid] * rsqrtf(var[tid] + BN_EPS);
        sInv[tid] = inv;
        sB[tid] = beta[tid] - mean[tid] * inv;
    }
    __syncthreads();
    int bid = blockIdx.x;          // 512 = 32 n * 16 pblk
    int n = bid >> 4;
    int p0 = (bid & 15) * 64;
    int l = tid & 63, wv = tid >> 6;   // wv == kc chunk
    int p = p0 + l;
    int y = p >> 5, x = p & 31;
    float delta = *deltaPtr;
    const float* sp = src + (size_t)n * 262144 + p;
    signed char* qp = qr + (size_t)wv * QR_KC + (size_t)n * QR_IMG +
                      (size_t)((y + 1) * 34 + (x + 1)) * 64;
#pragma unroll
    for (int chunk = 0; chunk < 4; ++chunk) {
        int w4[4];
#pragma unroll
        for (int d = 0; d < 4; ++d) {
            int wrd = 0;
#pragma unroll
            for (int j = 0; j < 4; ++j) {
                int c = wv * 64 + chunk * 16 + d * 4 + j;
                float s = sp[c * 1024] * sInv[c] + sB[c];
                int qv = s > delta ? 1 : (s < -delta ? -1 : 0);
                wrd |= (qv & 255) << (8 * j);
            }
            w4[d] = wrd;
        }
        int32x4 vv;
        vv[0] = w4[0]; vv[1] = w4[1]; vv[2] = w4[2]; vv[3] = w4[3];
        *(int32x4*)(qp + chunk * 16) = vv;
    }
}

// ---------------------------------------------------------------------------
// TBN conv, i8 MFMA 16x16x64. Block 256 thr = 4 waves (2x2); block tile
// 128(o) x 128(px); wave tile 64x64. Every fragment load = contiguous 1KB.
// Register double-buffer, 36 (tap,kc) steps fully unrolled.
// ---------------------------------------------------------------------------
template <bool FUSE>
__global__ __launch_bounds__(256, 2) void tbn_conv_kernel(
    const signed char* __restrict__ qr,   // [4][32][34][34][64] i8
    const signed char* __restrict__ Sr,   // [36][256][64] i8
    const float* __restrict__ alpha,      // [256]
    const float* __restrict__ resid,      // [32][256][1024] f32
    float* __restrict__ out,              // [32][256][1024] f32
    const float* __restrict__ gamma, const float* __restrict__ beta,
    const float* __restrict__ mean, const float* __restrict__ var,
    float* __restrict__ partials) {
    int bid = blockIdx.x;
    int wg = (bid & 7) * 64 + (bid >> 3);  // bijective, 512 % 8 == 0
    int n = wg >> 4;
    int pb = (wg >> 1) & 7;
    int ob = wg & 1;
    int tid = threadIdx.x, lane = tid & 63, wid = tid >> 6;
    int l15 = lane & 15, kg = lane >> 4;

    __shared__ float sAl[128], sInvS[128], sBS[128];
    __shared__ float red[256];
    if (tid < 128) {
        int o = ob * 128 + tid;
        sAl[tid] = alpha[o];
        if (FUSE) {
            float inv = gamma[o] * rsqrtf(var[o] + BN_EPS);
            sInvS[tid] = inv;
            sBS[tid] = beta[o] - mean[o] * inv;
        }
    }
    __syncthreads();

    int oW = (wid >> 1) * 64, pW = (wid & 1) * 64;

    // A lane base: Sr[(t*4+kc)*16384] + (o0+l15)*64 + kg*16 ; frag m at +m*1024
    const signed char* Abase = Sr + (size_t)(ob * 128 + oW + l15) * 64 + kg * 16;
    // B lane base per nn
    const signed char* Bbase = qr + (size_t)n * QR_IMG + kg * 16;
    int bOff[4], pL[4];
#pragma unroll
    for (int nn = 0; nn < 4; ++nn) {
        int p = pb * 128 + pW + nn * 16 + l15;
        pL[nn] = p;
        int pt = p - l15;               // tile origin, multiple of 16
        int y = pt >> 5, x = pt & 31;   // all 16 lanes share y
        bOff[nn] = ((y + 1) * 34 + (x + 1) + l15) * 64;
    }

    int32x4 acc[4][4];
#pragma unroll
    for (int m = 0; m < 4; ++m)
#pragma unroll
        for (int nn = 0; nn < 4; ++nn) {
            acc[m][nn][0] = 0; acc[m][nn][1] = 0;
            acc[m][nn][2] = 0; acc[m][nn][3] = 0;
        }

    int32x4 fa0[4], fb0[4], fa1[4], fb1[4];

#define LOADF(FA, FB, I)                                                      \
    do {                                                                      \
        const int i_ = (I);                                                   \
        const int t_ = i_ >> 2, kc_ = i_ & 3;                                 \
        const int kh1_ = t_ / 3, kw1_ = t_ % 3;                               \
        const int shift_ = ((kh1_ - 1) * 34 + (kw1_ - 1)) * 64;               \
        const signed char* pa_ = Abase + (size_t)i_ * SR_TAPKC;               \
        const signed char* pb_ = Bbase + (size_t)kc_ * QR_KC + shift_;        \
        FA[0] = *(const int32x4*)(pa_);                                       \
        FA[1] = *(const int32x4*)(pa_ + 1024);                                \
        FA[2] = *(const int32x4*)(pa_ + 2048);                                \
        FA[3] = *(const int32x4*)(pa_ + 3072);                                \
        FB[0] = *(const int32x4*)(pb_ + bOff[0]);                             \
        FB[1] = *(const int32x4*)(pb_ + bOff[1]);                             \
        FB[2] = *(const int32x4*)(pb_ + bOff[2]);                             \
        FB[3] = *(const int32x4*)(pb_ + bOff[3]);                             \
    } while (0)

#define MFMA16(FA, FB)                                                        \
    do {                                                                      \
        _Pragma("unroll")                                                     \
        for (int m = 0; m < 4; ++m)                                           \
            _Pragma("unroll")                                                 \
            for (int nn = 0; nn < 4; ++nn)                                    \
                acc[m][nn] = __builtin_amdgcn_mfma_i32_16x16x64_i8(           \
                    FA[m], FB[nn], acc[m][nn], 0, 0, 0);                      \
    } while (0)

    LOADF(fa0, fb0, 0);
#pragma unroll
    for (int i = 0; i < 36; i += 2) {
        LOADF(fa1, fb1, i + 1);
        MFMA16(fa0, fb0);
        if (i + 2 < 36) LOADF(fa0, fb0, i + 2);
        MFMA16(fa1, fb1);
    }
#undef LOADF
#undef MFMA16

    // D layout: col = l15 (pixel), row = kg*4 + r (o within 16)
    float psum = 0.f;
#pragma unroll
    for (int m = 0; m < 4; ++m) {
#pragma unroll
        for (int r = 0; r < 4; ++r) {
            int oLoc = oW + m * 16 + kg * 4 + r;  // 0..127
            int o = ob * 128 + oLoc;
            float al = sAl[oLoc];
            float inv = 0.f, bb = 0.f;
            if (FUSE) { inv = sInvS[oLoc]; bb = sBS[oLoc]; }
            const float* rp = resid + (size_t)n * 262144 + (size_t)o * 1024;
            float* op = out + (size_t)n * 262144 + (size_t)o * 1024;
#pragma unroll
            for (int nn = 0; nn < 4; ++nn) {
                float h = rp[pL[nn]] + al * (float)acc[m][nn][r];
                op[pL[nn]] = h;
                if (FUSE) psum += fabsf(h * inv + bb);
            }
        }
    }
    if (FUSE) {
        red[tid] = psum;
        __syncthreads();
        for (int off = 128; off > 0; off >>= 1) {
            if (tid < off) red[tid] += red[tid + off];
            __syncthreads();
        }
        if (tid == 0) partials[wg] = red[0];
    }
}

// ---------------------------------------------------------------------------
extern "C" void kernel_launch(void* const* d_in, const int* in_sizes, int n_in,
                              void* d_out, int out_size, void* d_ws, size_t ws_size,
                              hipStream_t stream) {
    (void)in_sizes; (void)n_in; (void)out_size; (void)ws_size;
    const float* x  = (const float*)d_in[0];
    const float* w1 = (const float*)d_in[1];
    const float* w2 = (const float*)d_in[2];
    const float* g1 = (const float*)d_in[3];
    const float* b1 = (const float*)d_in[4];
    const float* m1 = (const float*)d_in[5];
    const float* v1 = (const float*)d_in[6];
    const float* g2 = (const float*)d_in[7];
    const float* b2 = (const float*)d_in[8];
    const float* m2 = (const float*)d_in[9];
    const float* v2 = (const float*)d_in[10];
    float* out = (float*)d_out;
    char* ws = (char*)d_ws;

    float* delta1 = (float*)(ws + 0);
    float* delta2 = (float*)(ws + 4);
    float* red1   = (float*)(ws + 4096);       // 4096 floats
    float* redc   = (float*)(ws + 20480);      // 512 floats
    float* alpha1 = (float*)(ws + 24576);
    float* alpha2 = (float*)(ws + 25600);
    signed char* Sr1 = (signed char*)(ws + ((size_t)1 << 20));
    signed char* Sr2 = (signed char*)(ws + ((size_t)2 << 20));
    signed char* qr1 = (signed char*)(ws + ((size_t)4 << 20));
    signed char* qr2 = (signed char*)(ws + ((size_t)16 << 20));
    float* h         = (float*)(ws + ((size_t)32 << 20));

    const float kScale = 0.7f / 8388608.0f;

    hipMemsetAsync(qr1, 0, (size_t)4 * QR_KC, stream);
    hipMemsetAsync(qr2, 0, (size_t)4 * QR_KC, stream);
    prep_w_kernel<<<256, 256, 0, stream>>>(w1, Sr1, alpha1);
    prep_w_kernel<<<256, 256, 0, stream>>>(w2, Sr2, alpha2);
    bnabs_reduce_kernel<<<4096, 256, 0, stream>>>(x, g1, b1, m1, v1, red1);
    finalize_delta_kernel<<<1, 256, 0, stream>>>(red1, 4096, kScale, delta1);
    quant_kernel<<<512, 256, 0, stream>>>(x, g1, b1, m1, v1, delta1, qr1);
    tbn_conv_kernel<true><<<512, 256, 0, stream>>>(qr1, Sr1, alpha1, x, h,
                                                   g2, b2, m2, v2, redc);
    finalize_delta_kernel<<<1, 256, 0, stream>>>(redc, 512, kScale, delta2);
    quant_kernel<<<512, 256, 0, stream>>>(h, g2, b2, m2, v2, delta2, qr2);
    tbn_conv_kernel<false><<<512, 256, 0, stream>>>(qr2, Sr2, alpha2, h, out,
                                                    nullptr, nullptr, nullptr,
                                                    nullptr, nullptr);
}

// Round 4
// 124.267 us; speedup vs baseline: 3.0861x; 1.1563x over previous
//
#include <hip/hip_runtime.h>

#define BN_EPS 1e-5f

// q layout: [kc 4][kg 4][n 32][row 34][slot 64][16B]  (padded rows: 1 row = 1KB)
#define QR_ROW   1024
#define QR_IMG_P 34816            // 34 rows * 1KB
#define QR_KG    1114112          // 32 * QR_IMG_P
#define QR_KC4   4456448          // 4 * QR_KG
#define QR_TOTAL 17825792         // 4 * QR_KC4
#define SR_STEP  16384            // per (kc,t): 256 o * 64B

typedef __attribute__((ext_vector_type(4))) int int32x4;

#define GLOAD_LDS16(gptr, lptr)                                               \
    __builtin_amdgcn_global_load_lds(                                         \
        (const __attribute__((address_space(1))) unsigned int*)(gptr),        \
        (__attribute__((address_space(3))) unsigned int*)(lptr), 16, 0, 0)

// ---------------------------------------------------------------------------
// Weight prep: alpha[o] = mean|w[o]| ; Sr[(kc*9+t)*256 + o][64] = sign i8.
// ---------------------------------------------------------------------------
__global__ void prep_w_kernel(const float* __restrict__ w,
                              signed char* __restrict__ Sr,
                              float* __restrict__ alpha) {
    int o = blockIdx.x;   // 256
    int c = threadIdx.x;  // 256
    const float* wp = w + (o * 256 + c) * 9;
    float s = 0.f;
    __shared__ __align__(16) signed char lsg[9][256];
    __shared__ float red[256];
#pragma unroll
    for (int j = 0; j < 9; ++j) {
        float v = wp[j];
        s += fabsf(v);
        lsg[j][c] = v > 0.f ? 1 : (v < 0.f ? -1 : 0);
    }
    red[c] = s;
    __syncthreads();
    for (int off = 128; off > 0; off >>= 1) {
        if (c < off) red[c] += red[c + off];
        __syncthreads();
    }
    if (c == 0) alpha[o] = red[0] / 2304.0f;
    if (c < 144) {
        int t = c / 16, u = c % 16;
        int c0 = u * 16;
        int kc = c0 >> 6, cb = c0 & 63;
        int32x4 v = *(const int32x4*)(&lsg[t][c0]);
        *(int32x4*)(Sr + (size_t)((kc * 9 + t) * 256 + o) * 64 + cb) = v;
    }
}

// ---------------------------------------------------------------------------
// Zero the halo slots of both q buffers (rows 0/33 cols 0..33, cols 0/33).
// 2 buf * 4 kc * 4 kg * 32 n * 132 slots = 135168 threads.
// ---------------------------------------------------------------------------
__global__ void halo_zero_kernel(signed char* __restrict__ qr1,
                                 signed char* __restrict__ qr2) {
    int idx = blockIdx.x * 256 + threadIdx.x;
    int s = idx % 132;
    int rest = idx / 132;
    int n = rest & 31;
    int rest2 = rest >> 5;
    int kg = rest2 & 3;
    int kc = (rest2 >> 2) & 3;
    int b = rest2 >> 4;
    int r, cc;
    if (s < 34)       { r = 0;        cc = s; }
    else if (s < 68)  { r = 33;       cc = s - 34; }
    else if (s < 100) { r = s - 67;   cc = 0; }
    else              { r = s - 99;   cc = 33; }
    signed char* p = (b ? qr2 : qr1) + (size_t)kc * QR_KC4 + (size_t)kg * QR_KG +
                     (size_t)n * QR_IMG_P + (size_t)(r * 64 + cc) * 16;
    int32x4 z; z[0] = 0; z[1] = 0; z[2] = 0; z[3] = 0;
    *(int32x4*)p = z;
}

// ---------------------------------------------------------------------------
// partials[bid] = block-sum of |bn1(x)| (deterministic tree).
// ---------------------------------------------------------------------------
__global__ void bnabs_reduce_kernel(const float* __restrict__ x,
                                    const float* __restrict__ gamma,
                                    const float* __restrict__ beta,
                                    const float* __restrict__ mean,
                                    const float* __restrict__ var,
                                    float* __restrict__ partials) {
    int tid = blockIdx.x * blockDim.x + threadIdx.x;
    int nthreads = gridDim.x * blockDim.x;
    const float4* x4 = (const float4*)x;
    float s = 0.f;
    for (int i = tid; i < 2097152; i += nthreads) {
        int c = (i >> 8) & 255;
        float inv = gamma[c] * rsqrtf(var[c] + BN_EPS);
        float b = beta[c] - mean[c] * inv;
        float4 v = x4[i];
        s += fabsf(v.x * inv + b) + fabsf(v.y * inv + b) +
             fabsf(v.z * inv + b) + fabsf(v.w * inv + b);
    }
    __shared__ float red[256];
    red[threadIdx.x] = s;
    __syncthreads();
    for (int off = 128; off > 0; off >>= 1) {
        if (threadIdx.x < off) red[threadIdx.x] += red[threadIdx.x + off];
        __syncthreads();
    }
    if (threadIdx.x == 0) partials[blockIdx.x] = red[0];
}

__global__ void finalize_delta_kernel(const float* __restrict__ partials, int n,
                                      float scale, float* __restrict__ out) {
    __shared__ float red[256];
    float s = 0.f;
    for (int i = threadIdx.x; i < n; i += 256) s += partials[i];
    red[threadIdx.x] = s;
    __syncthreads();
    for (int off = 128; off > 0; off >>= 1) {
        if (threadIdx.x < off) red[threadIdx.x] += red[threadIdx.x + off];
        __syncthreads();
    }
    if (threadIdx.x == 0) *out = red[0] * scale;
}

// ---------------------------------------------------------------------------
// Quantize into padded layout q[kc][kg][n][y+1][x+1][16] (interior only).
// Block 256 thr = 64 px x 4 kc-slabs; 4 x 16B stores per thread.
// ---------------------------------------------------------------------------
__global__ __launch_bounds__(256) void quant_kernel(
    const float* __restrict__ src,
    const float* __restrict__ gamma, const float* __restrict__ beta,
    const float* __restrict__ mean, const float* __restrict__ var,
    const float* __restrict__ deltaPtr, signed char* __restrict__ qr) {
    __shared__ float sInv[256], sB[256];
    int tid = threadIdx.x;
    {
        float inv = gamma[tid] * rsqrtf(var[tid] + BN_EPS);
        sInv[tid] = inv;
        sB[tid] = beta[tid] - mean[tid] * inv;
    }
    __syncthreads();
    int bid = blockIdx.x;          // 512 = 32 n * 16 pblk
    int n = bid >> 4;
    int p0 = (bid & 15) * 64;
    int l = tid & 63, wv = tid >> 6;   // wv == kc
    int p = p0 + l;
    int y = p >> 5, x = p & 31;
    float delta = *deltaPtr;
    const float* sp = src + (size_t)n * 262144 + p;
    signed char* qp = qr + (size_t)wv * QR_KC4 + (size_t)n * QR_IMG_P +
                      (size_t)((y + 1) * 64 + (x + 1)) * 16;
#pragma unroll
    for (int kg = 0; kg < 4; ++kg) {
        int w4[4];
#pragma unroll
        for (int d = 0; d < 4; ++d) {
            int wrd = 0;
#pragma unroll
            for (int j = 0; j < 4; ++j) {
                int c = wv * 64 + kg * 16 + d * 4 + j;
                float s = sp[c * 1024] * sInv[c] + sB[c];
                int qv = s > delta ? 1 : (s < -delta ? -1 : 0);
                wrd |= (qv & 255) << (8 * j);
            }
            w4[d] = wrd;
        }
        int32x4 vv;
        vv[0] = w4[0]; vv[1] = w4[1]; vv[2] = w4[2]; vv[3] = w4[3];
        *(int32x4*)(qp + (size_t)kg * QR_KG) = vv;
    }
}

// ---------------------------------------------------------------------------
// TBN conv: i8 MFMA 16x16x64. 512 blocks x 256 thr (4 waves), block tile
// 128o x 128px, wave tile 64x64. B staged in LDS per kc (double-buffered,
// global_load_lds 1KB rows); A register ping-pong from L2-hot Sr.
// ---------------------------------------------------------------------------
template <bool FUSE>
__global__ __launch_bounds__(256, 2) void tbn_conv_kernel(
    const signed char* __restrict__ qr,   // padded layout (above)
    const signed char* __restrict__ Sr,   // [kc][t][256][64] i8
    const float* __restrict__ alpha,      // [256]
    const float* __restrict__ resid,      // [32][256][1024] f32
    float* __restrict__ out,              // [32][256][1024] f32
    const float* __restrict__ gamma, const float* __restrict__ beta,
    const float* __restrict__ mean, const float* __restrict__ var,
    float* __restrict__ partials) {
    __shared__ __align__(16) signed char Bl[2][24576];  // [kg 4][row 6][slot 64][16]
    __shared__ float sAl[128], sInvS[128], sBS[128];
    __shared__ float red[256];

    int bid = blockIdx.x;
    int wg = (bid & 7) * 64 + (bid >> 3);  // bijective, 512 % 8 == 0
    int n = wg >> 4;
    int pb = (wg >> 1) & 7;
    int ob = wg & 1;
    int tid = threadIdx.x, lane = tid & 63, wid = tid >> 6;
    int l15 = lane & 15, kg = lane >> 4;

    if (tid < 128) {
        int o = ob * 128 + tid;
        sAl[tid] = alpha[o];
        if (FUSE) {
            float inv = gamma[o] * rsqrtf(var[o] + BN_EPS);
            sInvS[tid] = inv;
            sBS[tid] = beta[o] - mean[o] * inv;
        }
    }

    int oW = (wid >> 1) * 64, pW = (wid & 1) * 64;
    int o0 = ob * 128 + oW;
    int y0 = pb * 4;  // first real row of the 128-px tile

    // A lane base: Sr + i*SR_STEP + (o0+l15)*64 + kg*16 ; frag m at +m*1024
    const signed char* Abase = Sr + (size_t)(o0 + l15) * 64 + kg * 16;

    // B ds byte offsets per nn (within one buffer), tap adds (kh*64+kw)*16
    int dsOff[4], pL[4];
#pragma unroll
    for (int nn = 0; nn < 4; ++nn) {
        int p = pb * 128 + pW + nn * 16 + l15;
        pL[nn] = p;
        int y = p >> 5, x = p & 31;
        dsOff[nn] = kg * 6144 + (((y - y0 + 1) * 64) + (x + 1)) * 16;
    }

    // staging: 24 chunks (kg 0..3 x row 0..5), wave wid takes q = wid + 4k
    const signed char* qsrc = qr + (size_t)n * QR_IMG_P + (size_t)lane * 16;
#define STAGE(KC, BUF)                                                        \
    do {                                                                      \
        _Pragma("unroll")                                                     \
        for (int k = 0; k < 6; ++k) {                                         \
            int q_ = wid + 4 * k;                                             \
            int kg_ = q_ / 6, r_ = q_ % 6;                                    \
            const signed char* g_ = qsrc + (size_t)(KC) * QR_KC4 +            \
                (size_t)kg_ * QR_KG + (size_t)(y0 + r_) * QR_ROW;             \
            GLOAD_LDS16(g_, &Bl[BUF][kg_ * 6144 + r_ * 1024]);                \
        }                                                                     \
    } while (0)

    int32x4 acc[4][4];
#pragma unroll
    for (int m = 0; m < 4; ++m)
#pragma unroll
        for (int nn = 0; nn < 4; ++nn) {
            acc[m][nn][0] = 0; acc[m][nn][1] = 0;
            acc[m][nn][2] = 0; acc[m][nn][3] = 0;
        }

    int32x4 fa[2][4], fb[2][4];

#define LOADA(PAR, I)                                                         \
    do {                                                                      \
        const signed char* pa_ = Abase + (size_t)(I) * SR_STEP;               \
        fa[PAR][0] = *(const int32x4*)(pa_);                                  \
        fa[PAR][1] = *(const int32x4*)(pa_ + 1024);                           \
        fa[PAR][2] = *(const int32x4*)(pa_ + 2048);                           \
        fa[PAR][3] = *(const int32x4*)(pa_ + 3072);                           \
    } while (0)

#define LOADB(PAR, BUF, T)                                                    \
    do {                                                                      \
        const int kh_ = (T) / 3 - 1, kw_ = (T) % 3 - 1;                       \
        const int ta_ = (kh_ * 64 + kw_) * 16;                                \
        fb[PAR][0] = *(const int32x4*)(&Bl[BUF][dsOff[0] + ta_]);             \
        fb[PAR][1] = *(const int32x4*)(&Bl[BUF][dsOff[1] + ta_]);             \
        fb[PAR][2] = *(const int32x4*)(&Bl[BUF][dsOff[2] + ta_]);             \
        fb[PAR][3] = *(const int32x4*)(&Bl[BUF][dsOff[3] + ta_]);             \
    } while (0)

#define MFMA16(AP, BP)                                                        \
    do {                                                                      \
        _Pragma("unroll")                                                     \
        for (int m = 0; m < 4; ++m)                                           \
            _Pragma("unroll")                                                 \
            for (int nn = 0; nn < 4; ++nn)                                    \
                acc[m][nn] = __builtin_amdgcn_mfma_i32_16x16x64_i8(           \
                    fa[AP][m], fb[BP][nn], acc[m][nn], 0, 0, 0);              \
    } while (0)

    STAGE(0, 0);
    LOADA(0, 0);
    __syncthreads();   // drains stage-0 vmem, publishes Bl[0] + sAl

#pragma unroll
    for (int kc = 0; kc < 4; ++kc) {
        const int buf = kc & 1;
        if (kc < 3) STAGE(kc + 1, buf ^ 1);
        LOADB(0, buf, 0);
#pragma unroll
        for (int t = 0; t < 9; ++t) {
            const int i = kc * 9 + t;
            if (i < 35) LOADA((i + 1) & 1, i + 1);
            if (t < 8) LOADB((t + 1) & 1, buf, t + 1);
            MFMA16(i & 1, t & 1);
        }
        __syncthreads();  // vmcnt(0)+lgkmcnt(0)+barrier: stage kc+1 ready
    }
#undef STAGE
#undef LOADA
#undef LOADB
#undef MFMA16

    // D layout: col = l15 (pixel), row = kg*4 + r (o within 16)
    float psum = 0.f;
#pragma unroll
    for (int m = 0; m < 4; ++m) {
#pragma unroll
        for (int r = 0; r < 4; ++r) {
            int oLoc = oW + m * 16 + kg * 4 + r;  // 0..127
            int o = ob * 128 + oLoc;
            float al = sAl[oLoc];
            float inv = 0.f, bb = 0.f;
            if (FUSE) { inv = sInvS[oLoc]; bb = sBS[oLoc]; }
            const float* rp = resid + (size_t)n * 262144 + (size_t)o * 1024;
            float* op = out + (size_t)n * 262144 + (size_t)o * 1024;
#pragma unroll
            for (int nn = 0; nn < 4; ++nn) {
                float h = rp[pL[nn]] + al * (float)acc[m][nn][r];
                op[pL[nn]] = h;
                if (FUSE) psum += fabsf(h * inv + bb);
            }
        }
    }
    if (FUSE) {
        red[tid] = psum;
        __syncthreads();
        for (int off = 128; off > 0; off >>= 1) {
            if (tid < off) red[tid] += red[tid + off];
            __syncthreads();
        }
        if (tid == 0) partials[wg] = red[0];
    }
}

// ---------------------------------------------------------------------------
extern "C" void kernel_launch(void* const* d_in, const int* in_sizes, int n_in,
                              void* d_out, int out_size, void* d_ws, size_t ws_size,
                              hipStream_t stream) {
    (void)in_sizes; (void)n_in; (void)out_size; (void)ws_size;
    const float* x  = (const float*)d_in[0];
    const float* w1 = (const float*)d_in[1];
    const float* w2 = (const float*)d_in[2];
    const float* g1 = (const float*)d_in[3];
    const float* b1 = (const float*)d_in[4];
    const float* m1 = (const float*)d_in[5];
    const float* v1 = (const float*)d_in[6];
    const float* g2 = (const float*)d_in[7];
    const float* b2 = (const float*)d_in[8];
    const float* m2 = (const float*)d_in[9];
    const float* v2 = (const float*)d_in[10];
    float* out = (float*)d_out;
    char* ws = (char*)d_ws;

    float* delta1 = (float*)(ws + 0);
    float* delta2 = (float*)(ws + 4);
    float* red1   = (float*)(ws + 4096);       // 4096 floats
    float* redc   = (float*)(ws + 20480);      // 512 floats
    float* alpha1 = (float*)(ws + 24576);
    float* alpha2 = (float*)(ws + 25600);
    signed char* Sr1 = (signed char*)(ws + ((size_t)1 << 20));
    signed char* Sr2 = (signed char*)(ws + ((size_t)2 << 20));
    signed char* qr1 = (signed char*)(ws + ((size_t)4 << 20));   // 17.8 MB
    signed char* qr2 = (signed char*)(ws + ((size_t)24 << 20));  // 17.8 MB
    float* h         = (float*)(ws + ((size_t)44 << 20));        // 134 MB

    const float kScale = 0.7f / 8388608.0f;

    halo_zero_kernel<<<528, 256, 0, stream>>>(qr1, qr2);
    prep_w_kernel<<<256, 256, 0, stream>>>(w1, Sr1, alpha1);
    prep_w_kernel<<<256, 256, 0, stream>>>(w2, Sr2, alpha2);
    bnabs_reduce_kernel<<<4096, 256, 0, stream>>>(x, g1, b1, m1, v1, red1);
    finalize_delta_kernel<<<1, 256, 0, stream>>>(red1, 4096, kScale, delta1);
    quant_kernel<<<512, 256, 0, stream>>>(x, g1, b1, m1, v1, delta1, qr1);
    tbn_conv_kernel<true><<<512, 256, 0, stream>>>(qr1, Sr1, alpha1, x, h,
                                                   g2, b2, m2, v2, redc);
    finalize_delta_kernel<<<1, 256, 0, stream>>>(redc, 512, kScale, delta2);
    quant_kernel<<<512, 256, 0, stream>>>(h, g2, b2, m2, v2, delta2, qr2);
    tbn_conv_kernel<false><<<512, 256, 0, stream>>>(qr2, Sr2, alpha2, h, out,
                                                    nullptr, nullptr, nullptr,
                                                    nullptr, nullptr);
}